// Round 9
// baseline (212.059 us; speedup 1.0000x reference)
//
#include <hip/hip_runtime.h>
#include <math.h>

// Rod_Block: N=8, C_IN=64, C_OUT=128, G=4, CG=16, K=3, P=9, PAD=1, H=W=64.
// All tensors fp32. Padded spatial 66x66.
// Round-24: R8's 8px/wave dwsamp regressed (59->74us: occupancy 38->25%,
// hbm_bytes 26->62MB) -> k_dwsamp reverted to R7 v4 (byte-identical).
// New: k_pool merged into k_xsproj via per-image last-block reduction:
// each (n,h) block's staged row tile IS its pool contribution; 64th
// arriver per image (device-scope atomicAdd) computes the gain MLP and
// release-stores flag[n]; others relaxed-poll + ONE acquire fence (R4
// lesson: no acquire in poll loop). All 512 blocks co-resident (34.4KB
// LDS -> 4 blk/CU -> cap 1024) => no deadlock. cnt/flag zeroed per replay
// by hipMemsetAsync (graph-legal). Nodes: memset + k_pre + k_dwsamp.

// Wave-local LDS fence (R16/R17).
#define WAVE_FENCE() asm volatile("s_waitcnt lgkmcnt(0)" ::: "memory")

// Packed-pair FMA: acc.{x,y} += s * v.{x,y} (v_pk_fma_f32 candidate).
__device__ __forceinline__ float2 fma2s(float s, float2 v, float2 acc) {
    acc.x = fmaf(s, v.x, acc.x);
    acc.y = fmaf(s, v.y, acc.y);
    return acc;
}

// ---- K_A: pool(in-block) + gain(last-block) + xs + input_proj + xpad ----
// 512 blocks x 256 threads; block = (n = b&7, h = b>>3).
__global__ __launch_bounds__(256) void k_pre(
        const float* x, const float* refl,
        const float* tap_w, const float* tap_b,
        const float* gw1, const float* gb1,
        const float* gw2, const float* gb2,
        const float* inp_w, const float* inp_b,
        int* sync, float* gaing, float* parts,
        float* xs, float* xpad) {
    __shared__ float tile[64][65];
    __shared__ float xsw[64][68];
    __shared__ float rr[64];
    __shared__ int comp;
    int t = threadIdx.x;
    int b = blockIdx.x;
    int n = b & 7, h = b >> 3;              // XCD-locality swizzle
    int c = t & 63, g = t >> 6;
    int* cnt  = sync;                        // [8]
    int* flag = sync + 8;                    // [8]

    // phase 1: stage x[n,:,h,:] -- 256B-coalesced per channel row
    #pragma unroll
    for (int it = 0; it < 4; ++it) {
        int f = it * 256 + t;               // float4 index in tile
        int cc = f >> 4, w4 = (f & 15) * 4;
        float4 v = *reinterpret_cast<const float4*>(
            &x[(((size_t)(n * 64 + cc)) * 64 + h) * 64 + w4]);
        tile[cc][w4 + 0] = v.x;
        tile[cc][w4 + 1] = v.y;
        tile[cc][w4 + 2] = v.z;
        tile[cc][w4 + 3] = v.w;
    }
    if (t < 64) rr[t] = refl[n * 4096 + h * 64 + t];
    __syncthreads();

    // pool partials: this row's per-channel sums (xsw rows 0..3 = scratch)
    {
        float rs = 0.f;
        #pragma unroll
        for (int k = 0; k < 16; ++k) rs += tile[c][g * 16 + k];
        xsw[g][c] = rs;
    }
    __syncthreads();
    if (t < 64) {
        float tot = xsw[0][t] + xsw[1][t] + xsw[2][t] + xsw[3][t];
        parts[((size_t)(n * 64 + h)) * 64 + t] = tot;
    }
    __syncthreads();      // scratch reads done; parts stores drained at barrier
    if (t == 0) {
        __threadfence();  // publish parts (agent scope: wbL2)
        int old = __hip_atomic_fetch_add(&cnt[n], 1, __ATOMIC_ACQ_REL,
                                         __HIP_MEMORY_SCOPE_AGENT);
        comp = (old == 63) ? 1 : 0;
    }
    __syncthreads();

    if (comp) {           // 64th arriver: reduce parts -> pooled -> gain MLP
        if (t < 64) {
            __builtin_amdgcn_fence(__ATOMIC_ACQUIRE, "agent");
            int lane = t;
            float pv = 0.f;
            for (int hh = 0; hh < 64; ++hh)
                pv += parts[((size_t)(n * 64 + hh)) * 64 + lane];
            pv *= (1.f / 4096.f);
            float part[16];
            const float4* g4 = reinterpret_cast<const float4*>(gw1 + lane * 16);
            #pragma unroll
            for (int q = 0; q < 4; ++q) {
                float4 v = g4[q];
                part[q * 4 + 0] = pv * v.x;
                part[q * 4 + 1] = pv * v.y;
                part[q * 4 + 2] = pv * v.z;
                part[q * 4 + 3] = pv * v.w;
            }
            #pragma unroll
            for (int o = 32; o > 0; o >>= 1) {
                #pragma unroll
                for (int j = 0; j < 16; ++j) part[j] += __shfl_xor(part[j], o, 64);
            }
            float acc = gb2[lane];
            #pragma unroll
            for (int j = 0; j < 16; ++j) {
                float hj = fmaxf(part[j] + gb1[j], 0.f);
                acc += hj * gw2[j * 64 + lane];
            }
            gaing[n * 64 + lane] = 1.f + 1.f / (1.f + __expf(-acc));
        }
        __syncthreads();
        if (t == 0) {
            __threadfence();
            __hip_atomic_store(&flag[n], 1, __ATOMIC_RELEASE,
                               __HIP_MEMORY_SCOPE_AGENT);
        }
    }
    // all blocks: relaxed poll + single acquire fence (no per-poll invalidate)
    if (t == 0) {
        while (__hip_atomic_load(&flag[n], __ATOMIC_RELAXED,
                                 __HIP_MEMORY_SCOPE_AGENT) == 0)
            __builtin_amdgcn_s_sleep(16);
        __builtin_amdgcn_fence(__ATOMIC_ACQUIRE, "agent");
    }
    __syncthreads();

    // phase 2: xs = x*gain + relu(refl*tapw+tapb); thread = (c, 16 w's)
    {
        float gv = gaing[n * 64 + c];
        float tw = tap_w[c], tb = tap_b[c];
        float* xsg = xs + (((size_t)(n * 64 + h)) * 64) * 64 + c;
        #pragma unroll
        for (int k = 0; k < 16; ++k) {
            int w = g * 16 + k;
            float r = fmaxf(rr[w] * tw + tb, 0.f);
            float v = tile[c][w] * gv + r;
            xsw[w][c] = v;
            xsg[(size_t)w * 64] = v;
        }
    }
    __syncthreads();

    // phase 3: input_proj; thread = (co = c, 16 w's); xsw reads broadcast
    {
        float acc[16];
        float bv = inp_b[c];
        #pragma unroll
        for (int k = 0; k < 16; ++k) acc[k] = bv;
        for (int c4 = 0; c4 < 64; c4 += 4) {
            float q0 = inp_w[(c4 + 0) * 64 + c];
            float q1 = inp_w[(c4 + 1) * 64 + c];
            float q2 = inp_w[(c4 + 2) * 64 + c];
            float q3 = inp_w[(c4 + 3) * 64 + c];
            #pragma unroll
            for (int k = 0; k < 16; ++k) {
                float4 d = *reinterpret_cast<const float4*>(&xsw[g * 16 + k][c4]);
                acc[k] += d.x * q0 + d.y * q1 + d.z * q2 + d.w * q3;
            }
        }
        const size_t rowb = (((size_t)n * 66) + (h + 1)) * 66;
        #pragma unroll
        for (int k = 0; k < 16; ++k) {
            int w = g * 16 + k;
            xpad[(rowb + (w + 1)) * 64 + c] = acc[k];
        }
        if (g == 0) xpad[rowb * 64 + c] = 0.f;
        if (g == 3) xpad[(rowb + 65) * 64 + c] = 0.f;
        if (h == 0 || h == 63) {
            const size_t base = ((((size_t)n * 66) + (h == 0 ? 0 : 65)) * 66) * 64;
            for (int i = t; i < 66 * 64; i += 256) xpad[base + i] = 0.f;
        }
    }
}

// ---- K_B: dwsamp v4 (byte-identical R7: 4096x128, 4px/wave, float2 pairs) ----
__global__ __launch_bounds__(128, 4) void k_dwsamp(const float* xs, const float* xpad,
                       const float* dw_w, const float* dw_b,
                       const float* ln_g, const float* ln_b,
                       const float* off_w, const float* off_b,
                       const float* mask_w, const float* mask_b,
                       const float* outp_w, const float* outp_b,
                       const float* bn1_g, const float* bn1_b,
                       const float* bn1_m, const float* bn1_v,
                       const float* conv_w, const float* conv_b,
                       const float* bn2_g, const float* bn2_b,
                       const float* bn2_m, const float* bn2_v,
                       float* out) {
    __shared__ float smem[2816];

    int tid = threadIdx.x;
    int lane = tid & 63, wv = tid >> 6;      // wv in {0,1}
    float*  chunk = smem + wv * 1408;
    int4*   sad   = reinterpret_cast<int4*>(chunk);           // [4][36]
    float*  dwr   = chunk;                                    // [4][64] aliases sad
    float4* swt   = reinterpret_cast<float4*>(chunk + 576);   // [4][36]
    float*  dcnl  = chunk + 1152;                             // [4][64]
    float*  mlog  = chunk + 1152;                             // [4][40] aliases dcnl

    int b = blockIdx.x;
    int n = b & 7;                           // XCD-locality swizzle
    int pos0 = (b >> 3) * 8 + wv * 4;        // wave's first pixel within image
    int h = pos0 >> 6, w0 = pos0 & 63;       // 4 consecutive w on one row

    // ---- Phase A: depthwise 3x3 (6-column shared halo) + LN + GELU, 4 pixels ----
    {
        float dwk[9];
        #pragma unroll
        for (int k = 0; k < 9; ++k) dwk[k] = dw_w[k * 64 + lane];
        float s[4];
        float bvv = dw_b[lane];
        #pragma unroll
        for (int p = 0; p < 4; ++p) s[p] = bvv;
        for (int ky = 0; ky < 3; ++ky) {
            int y = h + ky - 1;
            if (y < 0 || y > 63) continue;
            const float* xrow = xs + ((size_t)(n * 64 + y)) * 4096;
            float v[6];
            #pragma unroll
            for (int dx = 0; dx < 6; ++dx) {
                int x2 = w0 - 1 + dx;
                v[dx] = (x2 >= 0 && x2 <= 63) ? xrow[x2 * 64 + lane] : 0.f;
            }
            float k0 = dwk[ky * 3 + 0], k1 = dwk[ky * 3 + 1], k2 = dwk[ky * 3 + 2];
            #pragma unroll
            for (int p = 0; p < 4; ++p)
                s[p] += v[p] * k0 + v[p + 1] * k1 + v[p + 2] * k2;
        }
        float lngv = ln_g[lane], lnbv = ln_b[lane];
        #pragma unroll
        for (int p = 0; p < 4; ++p) {
            float sv = s[p];
            float sum = sv, sq = sv * sv;
            #pragma unroll
            for (int o = 32; o > 0; o >>= 1) {
                sum += __shfl_xor(sum, o, 64);
                sq  += __shfl_xor(sq,  o, 64);
            }
            float mu = sum * (1.f / 64.f);
            float var = sq * (1.f / 64.f) - mu * mu;
            float nrm = (sv - mu) * rsqrtf(var + 1e-6f) * lngv + lnbv;
            dwr[p * 64 + lane] = 0.5f * nrm * (1.f + erff(nrm * 0.70710678118654752f));
        }
    }
    WAVE_FENCE();

    // ---- Phase B: 108 projections x 4 pixels; lane L<54 owns j={2L,2L+1}.
    float2 a01[4];
    {
        int jb = lane * 2;
        const float* wptr;
        int stride;
        float b0 = 0.f, b1 = 0.f;
        if (lane < 36)      { wptr = off_w + jb;         stride = 72; b0 = off_b[jb];       b1 = off_b[jb + 1]; }
        else if (lane < 54) { wptr = mask_w + (jb - 72); stride = 36; b0 = mask_b[jb - 72]; b1 = mask_b[jb - 71]; }
        else                { wptr = off_w;              stride = 0; }
        #pragma unroll
        for (int p = 0; p < 4; ++p) a01[p] = make_float2(b0, b1);
        for (int c4 = 0; c4 < 64; c4 += 4) {
            float4 d0 = *reinterpret_cast<const float4*>(&dwr[0 * 64 + c4]);
            float4 d1 = *reinterpret_cast<const float4*>(&dwr[1 * 64 + c4]);
            float4 d2 = *reinterpret_cast<const float4*>(&dwr[2 * 64 + c4]);
            float4 d3 = *reinterpret_cast<const float4*>(&dwr[3 * 64 + c4]);
            float dk0[4] = {d0.x, d0.y, d0.z, d0.w};
            float dk1[4] = {d1.x, d1.y, d1.z, d1.w};
            float dk2[4] = {d2.x, d2.y, d2.z, d2.w};
            float dk3[4] = {d3.x, d3.y, d3.z, d3.w};
            #pragma unroll
            for (int k = 0; k < 4; ++k) {
                float2 w2 = *reinterpret_cast<const float2*>(wptr);
                wptr += stride;
                a01[0] = fma2s(dk0[k], w2, a01[0]);
                a01[1] = fma2s(dk1[k], w2, a01[1]);
                a01[2] = fma2s(dk2[k], w2, a01[2]);
                a01[3] = fma2s(dk3[k], w2, a01[3]);
            }
        }
        if (lane >= 36 && lane < 54) {
            int jm = lane * 2 - 72;           // 0..34 even
            #pragma unroll
            for (int p = 0; p < 4; ++p) {
                mlog[p * 40 + jm]     = a01[p].x;
                mlog[p * 40 + jm + 1] = a01[p].y;
            }
        }
    }
    WAVE_FENCE();

    // ---- Phase B2 (lanes 0..35): softmax + sampling coords/weights per pixel ----
    if (lane < 36) {
        int g = lane / 9, pp = lane - g * 9;
        #pragma unroll
        for (int p = 0; p < 4; ++p) {
            const float* lrow = &mlog[p * 40 + g * 9];
            float m = lrow[0];
            #pragma unroll
            for (int k = 1; k < 9; ++k) m = fmaxf(m, lrow[k]);
            float ssum = 0.f, ek = 0.f;
            #pragma unroll
            for (int k = 0; k < 9; ++k) {
                float e = __expf(lrow[k] - m);
                ssum += e;
                if (k == pp) ek = e;
            }
            float mk = ek / ssum;
            float px = (float)((w0 + p) + (pp / 3)) + a01[p].x;   // kernel grid w-outer/h-inner
            float py = (float)(h + (pp % 3)) + a01[p].y;
            float x0f = floorf(px), y0f = floorf(py);
            float wx = px - x0f, wy = py - y0f;
            int x0 = (int)x0f, y0 = (int)y0f;
            int x1 = x0 + 1, y1 = y0 + 1;
            int xc0 = min(max(x0, 0), 65), xc1 = min(max(x1, 0), 65);
            int yc0 = min(max(y0, 0), 65), yc1 = min(max(y1, 0), 65);
            float vx0 = (x0 >= 0 && x0 < 66) ? 1.f : 0.f;
            float vx1 = (x1 >= 0 && x1 < 66) ? 1.f : 0.f;
            float vy0 = (y0 >= 0 && y0 < 66) ? 1.f : 0.f;
            float vy1 = (y1 >= 0 && y1 < 66) ? 1.f : 0.f;
            float wx0 = (1.f - wx) * vx0, wx1 = wx * vx1;
            float wy0 = (1.f - wy) * vy0, wy1 = wy * vy1;
            swt[p * 36 + lane] = make_float4(mk * wy0 * wx0, mk * wy0 * wx1,
                                             mk * wy1 * wx0, mk * wy1 * wx1);
            sad[p * 36 + lane] = make_int4((yc0 * 66 + xc0) * 64, (yc0 * 66 + xc1) * 64,
                                           (yc1 * 66 + xc0) * 64, (yc1 * 66 + xc1) * 64);
        }
    }
    WAVE_FENCE();

    // ---- Phase C: bilinear deformable sampling, 4 pixels ----
    {
        int gb = (lane >> 4) * 9;
        const float* xpn = xpad + (size_t)n * 66 * 66 * 64;
        #pragma unroll
        for (int p = 0; p < 4; ++p) {
            float t0[9], t1[9], t2[9], t3[9];
            #pragma unroll
            for (int pp = 0; pp < 9; ++pp) {
                int4 a = sad[p * 36 + gb + pp];
                t0[pp] = xpn[a.x + lane];
                t1[pp] = xpn[a.y + lane];
                t2[pp] = xpn[a.z + lane];
                t3[pp] = xpn[a.w + lane];
            }
            float acc = 0.f;
            #pragma unroll
            for (int pp = 0; pp < 9; ++pp) {
                float4 cw = swt[p * 36 + gb + pp];
                acc += cw.x * t0[pp] + cw.y * t1[pp]
                     + cw.z * t2[pp] + cw.w * t3[pp];
            }
            dcnl[p * 64 + lane] = acc;
        }
    }
    WAVE_FENCE();

    // ---- Phase D: output_proj + BN1 + ReLU; pixel-paired float2 accums ----
    {
        float ob = outp_b[lane];
        float2 s01 = make_float2(ob, ob), s23 = make_float2(ob, ob);
        for (int c4 = 0; c4 < 64; c4 += 4) {
            float w0v = outp_w[(c4 + 0) * 64 + lane];
            float w1v = outp_w[(c4 + 1) * 64 + lane];
            float w2v = outp_w[(c4 + 2) * 64 + lane];
            float w3v = outp_w[(c4 + 3) * 64 + lane];
            float4 d0 = *reinterpret_cast<const float4*>(&dcnl[0 * 64 + c4]);
            float4 d1 = *reinterpret_cast<const float4*>(&dcnl[1 * 64 + c4]);
            float4 d2 = *reinterpret_cast<const float4*>(&dcnl[2 * 64 + c4]);
            float4 d3 = *reinterpret_cast<const float4*>(&dcnl[3 * 64 + c4]);
            s01 = fma2s(w0v, make_float2(d0.x, d1.x), s01);
            s01 = fma2s(w1v, make_float2(d0.y, d1.y), s01);
            s01 = fma2s(w2v, make_float2(d0.z, d1.z), s01);
            s01 = fma2s(w3v, make_float2(d0.w, d1.w), s01);
            s23 = fma2s(w0v, make_float2(d2.x, d3.x), s23);
            s23 = fma2s(w1v, make_float2(d2.y, d3.y), s23);
            s23 = fma2s(w2v, make_float2(d2.z, d3.z), s23);
            s23 = fma2s(w3v, make_float2(d2.w, d3.w), s23);
        }
        float sc = bn1_g[lane] * rsqrtf(bn1_v[lane] + 1e-5f);
        float sh = bn1_b[lane] - sc * bn1_m[lane];
        WAVE_FENCE();   // all reads of dcnl done before overwrite below
        dcnl[0 * 64 + lane] = fmaxf(sc * s01.x + sh, 0.f);
        dcnl[1 * 64 + lane] = fmaxf(sc * s01.y + sh, 0.f);
        dcnl[2 * 64 + lane] = fmaxf(sc * s23.x + sh, 0.f);
        dcnl[3 * 64 + lane] = fmaxf(sc * s23.y + sh, 0.f);
    }
    WAVE_FENCE();

    // ---- Phase E: 1x1 conv 64->128 + BN2 + ReLU; channel-paired float2 ----
    {
        float2 acc2[4];   // [px]: .x -> d=lane, .y -> d=lane+64
        #pragma unroll
        for (int p = 0; p < 4; ++p) acc2[p] = make_float2(0.f, 0.f);
        for (int c4 = 0; c4 < 64; c4 += 4) {
            float4 d0 = *reinterpret_cast<const float4*>(&dcnl[0 * 64 + c4]);
            float4 d1 = *reinterpret_cast<const float4*>(&dcnl[1 * 64 + c4]);
            float4 d2 = *reinterpret_cast<const float4*>(&dcnl[2 * 64 + c4]);
            float4 d3 = *reinterpret_cast<const float4*>(&dcnl[3 * 64 + c4]);
            float dk0[4] = {d0.x, d0.y, d0.z, d0.w};
            float dk1[4] = {d1.x, d1.y, d1.z, d1.w};
            float dk2[4] = {d2.x, d2.y, d2.z, d2.w};
            float dk3[4] = {d3.x, d3.y, d3.z, d3.w};
            #pragma unroll
            for (int k = 0; k < 4; ++k) {
                float2 w2 = make_float2(conv_w[(c4 + k) * 128 + lane],
                                        conv_w[(c4 + k) * 128 + 64 + lane]);
                acc2[0] = fma2s(dk0[k], w2, acc2[0]);
                acc2[1] = fma2s(dk1[k], w2, acc2[1]);
                acc2[2] = fma2s(dk2[k], w2, acc2[2]);
                acc2[3] = fma2s(dk3[k], w2, acc2[3]);
            }
        }
        int dA = lane, dB = lane + 64;
        float scA = bn2_g[dA] * rsqrtf(bn2_v[dA] + 1e-5f);
        float shA = scA * (conv_b[dA] - bn2_m[dA]) + bn2_b[dA];
        float scB = bn2_g[dB] * rsqrtf(bn2_v[dB] + 1e-5f);
        float shB = scB * (conv_b[dB] - bn2_m[dB]) + bn2_b[dB];
        float4 rA, rB;
        rA.x = fmaxf(scA * acc2[0].x + shA, 0.f);
        rA.y = fmaxf(scA * acc2[1].x + shA, 0.f);
        rA.z = fmaxf(scA * acc2[2].x + shA, 0.f);
        rA.w = fmaxf(scA * acc2[3].x + shA, 0.f);
        rB.x = fmaxf(scB * acc2[0].y + shB, 0.f);
        rB.y = fmaxf(scB * acc2[1].y + shB, 0.f);
        rB.z = fmaxf(scB * acc2[2].y + shB, 0.f);
        rB.w = fmaxf(scB * acc2[3].y + shB, 0.f);
        size_t oA = (((size_t)(n * 128 + dA)) * 64 + h) * 64 + w0;
        size_t oB = (((size_t)(n * 128 + dB)) * 64 + h) * 64 + w0;
        *reinterpret_cast<float4*>(out + oA) = rA;
        *reinterpret_cast<float4*>(out + oB) = rB;
    }
}

extern "C" void kernel_launch(void* const* d_in, const int* in_sizes, int n_in,
                              void* d_out, int out_size, void* d_ws, size_t ws_size,
                              hipStream_t stream) {
    const float* x      = (const float*)d_in[0];
    const float* refl   = (const float*)d_in[1];
    const float* gw1    = (const float*)d_in[2];
    const float* gb1    = (const float*)d_in[3];
    const float* gw2    = (const float*)d_in[4];
    const float* gb2    = (const float*)d_in[5];
    const float* tap_w  = (const float*)d_in[6];
    const float* tap_b  = (const float*)d_in[7];
    const float* dw_w   = (const float*)d_in[8];
    const float* dw_b   = (const float*)d_in[9];
    const float* ln_g   = (const float*)d_in[10];
    const float* ln_b   = (const float*)d_in[11];
    const float* inp_w  = (const float*)d_in[12];
    const float* inp_b  = (const float*)d_in[13];
    const float* off_w  = (const float*)d_in[14];
    const float* off_b  = (const float*)d_in[15];
    const float* mask_w = (const float*)d_in[16];
    const float* mask_b = (const float*)d_in[17];
    const float* outp_w = (const float*)d_in[18];
    const float* outp_b = (const float*)d_in[19];
    const float* conv_w = (const float*)d_in[20];
    const float* conv_b = (const float*)d_in[21];
    const float* bn1_g  = (const float*)d_in[22];
    const float* bn1_b  = (const float*)d_in[23];
    const float* bn1_m  = (const float*)d_in[24];
    const float* bn1_v  = (const float*)d_in[25];
    const float* bn2_g  = (const float*)d_in[26];
    const float* bn2_b  = (const float*)d_in[27];
    const float* bn2_m  = (const float*)d_in[28];
    const float* bn2_v  = (const float*)d_in[29];

    // ws (floats): sync 16 ints | gain 512 | parts 32768 | xs 2,097,152 | xpad 2,230,272
    float* ws     = (float*)d_ws;
    int*   sync   = (int*)ws;              // cnt[8] + flag[8]
    float* gaing  = ws + 16;               // 512
    float* parts  = ws + 528;              // 32768 (8 images x 64 rows x 64 ch)
    float* xs     = ws + 33296;            // 2,097,152  (NHWC)
    float* xpad   = xs + 2097152;          // 2,230,272  (8*66*66*64, NHWC padded)

    hipMemsetAsync(sync, 0, 16 * sizeof(int), stream);
    k_pre<<<512, 256, 0, stream>>>(x, refl, tap_w, tap_b,
                                   gw1, gb1, gw2, gb2, inp_w, inp_b,
                                   sync, gaing, parts, xs, xpad);
    k_dwsamp<<<4096, 128, 0, stream>>>(xs, xpad, dw_w, dw_b, ln_g, ln_b,
                                       off_w, off_b, mask_w, mask_b,
                                       outp_w, outp_b, bn1_g, bn1_b, bn1_m, bn1_v,
                                       conv_w, conv_b, bn2_g, bn2_b, bn2_m, bn2_v,
                                       (float*)d_out);
}

// Round 10
// 202.232 us; speedup vs baseline: 1.0486x; 1.0486x over previous
//
#include <hip/hip_runtime.h>
#include <math.h>

// Rod_Block: N=8, C_IN=64, C_OUT=128, G=4, CG=16, K=3, P=9, PAD=1, H=W=64.
// All tensors fp32. Padded spatial 66x66.
// Round-25: revert to R7 3-dispatch structure (R9's last-block merge cost
// ~20us; every device-side sync scheme has lost to dispatch boundaries).
// New: x-PAIRED xpad layout — xpad2[y][x][c] = (V[x], V[x+1]) as float2.
// Phase C bilinear gathers become 2 float2 loads/tap instead of 4 scalar
// loads: 576 -> 288 VMEM issues per wave, sad int4 -> int2, LDS 11264 ->
// 8960B, C-phase FMAs pk-paired. B2 folds clamp edges into pair weights
// (wl/wr predicates; verified x0 in {<-1,-1,[0,64],65,>=66}).
// k_pool byte-identical; xsproj writes pair layout (8B-coalesced stores).

// Wave-local LDS fence (R16/R17).
#define WAVE_FENCE() asm volatile("s_waitcnt lgkmcnt(0)" ::: "memory")

// Packed-pair FMA helpers (v_pk_fma_f32 candidates).
__device__ __forceinline__ float2 fma2s(float s, float2 v, float2 acc) {
    acc.x = fmaf(s, v.x, acc.x);
    acc.y = fmaf(s, v.y, acc.y);
    return acc;
}
__device__ __forceinline__ float2 fma22(float2 a, float2 v, float2 acc) {
    acc.x = fmaf(a.x, v.x, acc.x);
    acc.y = fmaf(a.y, v.y, acc.y);
    return acc;
}

// ---- K1: pooled[n,c] = mean_{h,w} x[n,c,h,w]  (512 blocks x 256) ----
__global__ __launch_bounds__(256) void k_pool(const float* x, float* pooled) {
    __shared__ float red[256];
    int b = blockIdx.x;
    int nc = ((b & 7) << 6) | (b >> 3);     // n = b%8, c = b/8
    const float4* p4 = reinterpret_cast<const float4*>(x + (size_t)nc * 4096);
    float s = 0.f;
    for (int i = threadIdx.x; i < 1024; i += 256) {
        float4 v = p4[i];
        s += v.x + v.y + v.z + v.w;
    }
    red[threadIdx.x] = s;
    __syncthreads();
    for (int o = 128; o > 0; o >>= 1) {
        if (threadIdx.x < o) red[threadIdx.x] += red[threadIdx.x + o];
        __syncthreads();
    }
    if (threadIdx.x == 0) pooled[nc] = red[0] * (1.f / 4096.f);
}

// ---- K2: gain-MLP (in-block) + xs(NHWC) + input_proj -> paired xpad ----
// 512 blocks x 256 threads; block = (n = b&7, h = b>>3).
__global__ __launch_bounds__(256) void k_xsproj(
        const float* x, const float* refl,
        const float* tap_w, const float* tap_b,
        const float* pooled,
        const float* gw1, const float* gb1,
        const float* gw2, const float* gb2,
        const float* inp_w, const float* inp_b,
        float* xs, float* xpad2) {
    __shared__ float tile[64][65];
    __shared__ float xsw[64][68];
    __shared__ float rr[64];
    __shared__ float gbuf[64];
    int t = threadIdx.x;
    int b = blockIdx.x;
    int n = b & 7, h = b >> 3;              // XCD-locality swizzle
    int c = t & 63, g = t >> 6;             // phase2/3 mapping

    // phase 1: stage x[n,:,h,:] -- 256B-coalesced per channel row
    #pragma unroll
    for (int it = 0; it < 4; ++it) {
        int f = it * 256 + t;               // float4 index in tile
        int cc = f >> 4, w4 = (f & 15) * 4;
        float4 v = *reinterpret_cast<const float4*>(
            &x[(((size_t)(n * 64 + cc)) * 64 + h) * 64 + w4]);
        tile[cc][w4 + 0] = v.x;
        tile[cc][w4 + 1] = v.y;
        tile[cc][w4 + 2] = v.z;
        tile[cc][w4 + 3] = v.w;
    }
    if (t < 64) rr[t] = refl[n * 4096 + h * 64 + t];
    // wave 1: gain[n][lane] = 1 + sigmoid(MLP(pooled[n,:])) -- ~0.25us
    if (t >= 64 && t < 128) {
        int lane = t - 64;
        float pv = pooled[n * 64 + lane];
        float part[16];
        const float4* g4 = reinterpret_cast<const float4*>(gw1 + lane * 16);
        #pragma unroll
        for (int q = 0; q < 4; ++q) {
            float4 v = g4[q];
            part[q * 4 + 0] = pv * v.x;
            part[q * 4 + 1] = pv * v.y;
            part[q * 4 + 2] = pv * v.z;
            part[q * 4 + 3] = pv * v.w;
        }
        #pragma unroll
        for (int o = 32; o > 0; o >>= 1) {
            #pragma unroll
            for (int j = 0; j < 16; ++j) part[j] += __shfl_xor(part[j], o, 64);
        }
        float acc = gb2[lane];
        #pragma unroll
        for (int j = 0; j < 16; ++j) {
            float hj = fmaxf(part[j] + gb1[j], 0.f);
            acc += hj * gw2[j * 64 + lane];
        }
        gbuf[lane] = 1.f + 1.f / (1.f + __expf(-acc));
    }
    __syncthreads();

    // phase 2: xs = x*gain + relu(refl*tapw+tapb); thread = (c, 16 w's)
    {
        float gv = gbuf[c];
        float tw = tap_w[c], tb = tap_b[c];
        float* xsg = xs + (((size_t)(n * 64 + h)) * 64) * 64 + c;
        #pragma unroll
        for (int k = 0; k < 16; ++k) {
            int w = g * 16 + k;
            float r = fmaxf(rr[w] * tw + tb, 0.f);
            float v = tile[c][w] * gv + r;
            xsw[w][c] = v;
            xsg[(size_t)w * 64] = v;
        }
    }
    __syncthreads();

    // phase 3: input_proj; thread = (co = c, 16 w's); writes PAIR layout:
    // xpad2 element (y, xb, c, s) at ((y*66+xb)*128 + c*2 + s); pair xb
    // holds (V[xb], V[xb+1]). Value at x=w+1 goes to pair[x].x, pair[x-1].y.
    {
        float acc[16];
        float bv = inp_b[c];
        #pragma unroll
        for (int k = 0; k < 16; ++k) acc[k] = bv;
        for (int c4 = 0; c4 < 64; c4 += 4) {
            float q0 = inp_w[(c4 + 0) * 64 + c];
            float q1 = inp_w[(c4 + 1) * 64 + c];
            float q2 = inp_w[(c4 + 2) * 64 + c];
            float q3 = inp_w[(c4 + 3) * 64 + c];
            #pragma unroll
            for (int k = 0; k < 16; ++k) {
                float4 d = *reinterpret_cast<const float4*>(&xsw[g * 16 + k][c4]);
                acc[k] += d.x * q0 + d.y * q1 + d.z * q2 + d.w * q3;
            }
        }
        const size_t rowb = (((size_t)n * 66) + (h + 1)) * 66;   // in x units
        #pragma unroll
        for (int k = 0; k < 16; ++k) {
            int xx = g * 16 + k + 1;     // x position of this value
            float v = acc[k];
            xpad2[(rowb + xx) * 128 + c * 2 + 0]     = v;   // pair xx, left
            xpad2[(rowb + xx - 1) * 128 + c * 2 + 1] = v;   // pair xx-1, right
        }
        if (g == 0) xpad2[rowb * 128 + c * 2 + 0] = 0.f;          // V[0]
        if (g == 3) xpad2[(rowb + 64) * 128 + c * 2 + 1] = 0.f;   // V[65]
        if (h == 0 || h == 63) {
            const size_t base = ((((size_t)n * 66) + (h == 0 ? 0 : 65)) * 66) * 128;
            for (int i = t; i < 66 * 128; i += 256) xpad2[base + i] = 0.f;
        }
    }
}

// ---- K3: dwsamp v6 — R7 v4 + paired-gather Phase C ----
// 4096 blocks x 128 (2 independent waves); 4 px per wave.
// Per-wave LDS chunk of 1120 floats with phase-lifetime unions:
//   [0   .. 288)  sad2 [4][36] int2  (B2->C)  | dwr [4][64] (A->B)
//   [288 .. 864)  swt  [4][36] float4 (B2->C)
//   [864 .. 1120) dcnl [4][64] (C->E)         | mlog [4][40] (B->B2)
// Total 2*1120*4 = 8960 B per block.
__global__ __launch_bounds__(128, 4) void k_dwsamp(const float* xs, const float* xpad2,
                       const float* dw_w, const float* dw_b,
                       const float* ln_g, const float* ln_b,
                       const float* off_w, const float* off_b,
                       const float* mask_w, const float* mask_b,
                       const float* outp_w, const float* outp_b,
                       const float* bn1_g, const float* bn1_b,
                       const float* bn1_m, const float* bn1_v,
                       const float* conv_w, const float* conv_b,
                       const float* bn2_g, const float* bn2_b,
                       const float* bn2_m, const float* bn2_v,
                       float* out) {
    __shared__ float smem[2240];

    int tid = threadIdx.x;
    int lane = tid & 63, wv = tid >> 6;      // wv in {0,1}
    float*  chunk = smem + wv * 1120;
    int2*   sad2  = reinterpret_cast<int2*>(chunk);           // [4][36]
    float*  dwr   = chunk;                                    // [4][64] aliases sad2
    float4* swt   = reinterpret_cast<float4*>(chunk + 288);   // [4][36]
    float*  dcnl  = chunk + 864;                              // [4][64]
    float*  mlog  = chunk + 864;                              // [4][40] aliases dcnl

    int b = blockIdx.x;
    int n = b & 7;                           // XCD-locality swizzle
    int pos0 = (b >> 3) * 8 + wv * 4;        // wave's first pixel within image
    int h = pos0 >> 6, w0 = pos0 & 63;       // 4 consecutive w on one row

    // ---- Phase A: depthwise 3x3 (6-column shared halo) + LN + GELU, 4 pixels ----
    {
        float dwk[9];
        #pragma unroll
        for (int k = 0; k < 9; ++k) dwk[k] = dw_w[k * 64 + lane];
        float s[4];
        float bvv = dw_b[lane];
        #pragma unroll
        for (int p = 0; p < 4; ++p) s[p] = bvv;
        for (int ky = 0; ky < 3; ++ky) {
            int y = h + ky - 1;
            if (y < 0 || y > 63) continue;
            const float* xrow = xs + ((size_t)(n * 64 + y)) * 4096;
            float v[6];
            #pragma unroll
            for (int dx = 0; dx < 6; ++dx) {
                int x2 = w0 - 1 + dx;
                v[dx] = (x2 >= 0 && x2 <= 63) ? xrow[x2 * 64 + lane] : 0.f;
            }
            float k0 = dwk[ky * 3 + 0], k1 = dwk[ky * 3 + 1], k2 = dwk[ky * 3 + 2];
            #pragma unroll
            for (int p = 0; p < 4; ++p)
                s[p] += v[p] * k0 + v[p + 1] * k1 + v[p + 2] * k2;
        }
        float lngv = ln_g[lane], lnbv = ln_b[lane];
        #pragma unroll
        for (int p = 0; p < 4; ++p) {
            float sv = s[p];
            float sum = sv, sq = sv * sv;
            #pragma unroll
            for (int o = 32; o > 0; o >>= 1) {
                sum += __shfl_xor(sum, o, 64);
                sq  += __shfl_xor(sq,  o, 64);
            }
            float mu = sum * (1.f / 64.f);
            float var = sq * (1.f / 64.f) - mu * mu;
            float nrm = (sv - mu) * rsqrtf(var + 1e-6f) * lngv + lnbv;
            dwr[p * 64 + lane] = 0.5f * nrm * (1.f + erff(nrm * 0.70710678118654752f));
        }
    }
    WAVE_FENCE();

    // ---- Phase B: 108 projections x 4 pixels; lane L<54 owns j={2L,2L+1}.
    float2 a01[4];
    {
        int jb = lane * 2;
        const float* wptr;
        int stride;
        float b0 = 0.f, b1 = 0.f;
        if (lane < 36)      { wptr = off_w + jb;         stride = 72; b0 = off_b[jb];       b1 = off_b[jb + 1]; }
        else if (lane < 54) { wptr = mask_w + (jb - 72); stride = 36; b0 = mask_b[jb - 72]; b1 = mask_b[jb - 71]; }
        else                { wptr = off_w;              stride = 0; }
        #pragma unroll
        for (int p = 0; p < 4; ++p) a01[p] = make_float2(b0, b1);
        for (int c4 = 0; c4 < 64; c4 += 4) {
            float4 d0 = *reinterpret_cast<const float4*>(&dwr[0 * 64 + c4]);
            float4 d1 = *reinterpret_cast<const float4*>(&dwr[1 * 64 + c4]);
            float4 d2 = *reinterpret_cast<const float4*>(&dwr[2 * 64 + c4]);
            float4 d3 = *reinterpret_cast<const float4*>(&dwr[3 * 64 + c4]);
            float dk0[4] = {d0.x, d0.y, d0.z, d0.w};
            float dk1[4] = {d1.x, d1.y, d1.z, d1.w};
            float dk2[4] = {d2.x, d2.y, d2.z, d2.w};
            float dk3[4] = {d3.x, d3.y, d3.z, d3.w};
            #pragma unroll
            for (int k = 0; k < 4; ++k) {
                float2 w2 = *reinterpret_cast<const float2*>(wptr);
                wptr += stride;
                a01[0] = fma2s(dk0[k], w2, a01[0]);
                a01[1] = fma2s(dk1[k], w2, a01[1]);
                a01[2] = fma2s(dk2[k], w2, a01[2]);
                a01[3] = fma2s(dk3[k], w2, a01[3]);
            }
        }
        if (lane >= 36 && lane < 54) {
            int jm = lane * 2 - 72;           // 0..34 even
            #pragma unroll
            for (int p = 0; p < 4; ++p) {
                mlog[p * 40 + jm]     = a01[p].x;
                mlog[p * 40 + jm + 1] = a01[p].y;
            }
        }
    }
    WAVE_FENCE();

    // ---- Phase B2 (lanes 0..35): softmax + PAIR-based coords/weights ----
    if (lane < 36) {
        int g = lane / 9, pp = lane - g * 9;
        #pragma unroll
        for (int p = 0; p < 4; ++p) {
            const float* lrow = &mlog[p * 40 + g * 9];
            float m = lrow[0];
            #pragma unroll
            for (int k = 1; k < 9; ++k) m = fmaxf(m, lrow[k]);
            float ssum = 0.f, ek = 0.f;
            #pragma unroll
            for (int k = 0; k < 9; ++k) {
                float e = __expf(lrow[k] - m);
                ssum += e;
                if (k == pp) ek = e;
            }
            float mk = ek / ssum;
            float px = (float)((w0 + p) + (pp / 3)) + a01[p].x;   // w-outer/h-inner
            float py = (float)(h + (pp % 3)) + a01[p].y;
            float x0f = floorf(px), y0f = floorf(py);
            float wx = px - x0f, wy = py - y0f;
            int x0 = (int)x0f, y0 = (int)y0f;
            int x1 = x0 + 1, y1 = y0 + 1;
            int yc0 = min(max(y0, 0), 65), yc1 = min(max(y1, 0), 65);
            float vy0 = (y0 >= 0 && y0 < 66) ? 1.f : 0.f;
            float vy1 = (y1 >= 0 && y1 < 66) ? 1.f : 0.f;
            int xc0 = min(max(x0, 0), 65), xc1 = min(max(x1, 0), 65);
            float wx0 = ((x0 >= 0 && x0 < 66) ? 1.f : 0.f) * (1.f - wx);
            float wx1 = ((x1 >= 0 && x1 < 66) ? 1.f : 0.f) * wx;
            // fold clamped corners onto the pair (xb, xb+1):
            int xb = min(max(x0, 0), 64);
            float wl = (xc0 == xb     ? wx0 : 0.f) + (xc1 == xb     ? wx1 : 0.f);
            float wr = (xc0 == xb + 1 ? wx0 : 0.f) + (xc1 == xb + 1 ? wx1 : 0.f);
            float wy0m = mk * ((1.f - wy) * vy0);
            float wy1m = mk * (wy * vy1);
            swt[p * 36 + lane]  = make_float4(wy0m * wl, wy0m * wr,
                                              wy1m * wl, wy1m * wr);
            sad2[p * 36 + lane] = make_int2((yc0 * 66 + xb) * 128,
                                            (yc1 * 66 + xb) * 128);
        }
    }
    WAVE_FENCE();

    // ---- Phase C: bilinear sampling, paired float2 gathers (288 VMEM/wave) ----
    {
        int gb = (lane >> 4) * 9;
        const float* xpn = xpad2 + (size_t)n * 66 * 66 * 128;
        #pragma unroll
        for (int p = 0; p < 4; ++p) {
            float2 t0[9], t1[9];
            #pragma unroll
            for (int pp = 0; pp < 9; ++pp) {
                int2 a = sad2[p * 36 + gb + pp];
                t0[pp] = *reinterpret_cast<const float2*>(xpn + a.x + lane * 2);
                t1[pp] = *reinterpret_cast<const float2*>(xpn + a.y + lane * 2);
            }
            float2 acc2 = make_float2(0.f, 0.f);
            #pragma unroll
            for (int pp = 0; pp < 9; ++pp) {
                float4 cw = swt[p * 36 + gb + pp];
                acc2 = fma22(make_float2(cw.x, cw.y), t0[pp], acc2);
                acc2 = fma22(make_float2(cw.z, cw.w), t1[pp], acc2);
            }
            dcnl[p * 64 + lane] = acc2.x + acc2.y;
        }
    }
    WAVE_FENCE();

    // ---- Phase D: output_proj + BN1 + ReLU; pixel-paired float2 accums ----
    {
        float ob = outp_b[lane];
        float2 s01 = make_float2(ob, ob), s23 = make_float2(ob, ob);
        for (int c4 = 0; c4 < 64; c4 += 4) {
            float w0v = outp_w[(c4 + 0) * 64 + lane];
            float w1v = outp_w[(c4 + 1) * 64 + lane];
            float w2v = outp_w[(c4 + 2) * 64 + lane];
            float w3v = outp_w[(c4 + 3) * 64 + lane];
            float4 d0 = *reinterpret_cast<const float4*>(&dcnl[0 * 64 + c4]);
            float4 d1 = *reinterpret_cast<const float4*>(&dcnl[1 * 64 + c4]);
            float4 d2 = *reinterpret_cast<const float4*>(&dcnl[2 * 64 + c4]);
            float4 d3 = *reinterpret_cast<const float4*>(&dcnl[3 * 64 + c4]);
            s01 = fma2s(w0v, make_float2(d0.x, d1.x), s01);
            s01 = fma2s(w1v, make_float2(d0.y, d1.y), s01);
            s01 = fma2s(w2v, make_float2(d0.z, d1.z), s01);
            s01 = fma2s(w3v, make_float2(d0.w, d1.w), s01);
            s23 = fma2s(w0v, make_float2(d2.x, d3.x), s23);
            s23 = fma2s(w1v, make_float2(d2.y, d3.y), s23);
            s23 = fma2s(w2v, make_float2(d2.z, d3.z), s23);
            s23 = fma2s(w3v, make_float2(d2.w, d3.w), s23);
        }
        float sc = bn1_g[lane] * rsqrtf(bn1_v[lane] + 1e-5f);
        float sh = bn1_b[lane] - sc * bn1_m[lane];
        WAVE_FENCE();   // all reads of dcnl done before overwrite below
        dcnl[0 * 64 + lane] = fmaxf(sc * s01.x + sh, 0.f);
        dcnl[1 * 64 + lane] = fmaxf(sc * s01.y + sh, 0.f);
        dcnl[2 * 64 + lane] = fmaxf(sc * s23.x + sh, 0.f);
        dcnl[3 * 64 + lane] = fmaxf(sc * s23.y + sh, 0.f);
    }
    WAVE_FENCE();

    // ---- Phase E: 1x1 conv 64->128 + BN2 + ReLU; channel-paired float2 ----
    {
        float2 acc2[4];   // [px]: .x -> d=lane, .y -> d=lane+64
        #pragma unroll
        for (int p = 0; p < 4; ++p) acc2[p] = make_float2(0.f, 0.f);
        for (int c4 = 0; c4 < 64; c4 += 4) {
            float4 d0 = *reinterpret_cast<const float4*>(&dcnl[0 * 64 + c4]);
            float4 d1 = *reinterpret_cast<const float4*>(&dcnl[1 * 64 + c4]);
            float4 d2 = *reinterpret_cast<const float4*>(&dcnl[2 * 64 + c4]);
            float4 d3 = *reinterpret_cast<const float4*>(&dcnl[3 * 64 + c4]);
            float dk0[4] = {d0.x, d0.y, d0.z, d0.w};
            float dk1[4] = {d1.x, d1.y, d1.z, d1.w};
            float dk2[4] = {d2.x, d2.y, d2.z, d2.w};
            float dk3[4] = {d3.x, d3.y, d3.z, d3.w};
            #pragma unroll
            for (int k = 0; k < 4; ++k) {
                float2 w2 = make_float2(conv_w[(c4 + k) * 128 + lane],
                                        conv_w[(c4 + k) * 128 + 64 + lane]);
                acc2[0] = fma2s(dk0[k], w2, acc2[0]);
                acc2[1] = fma2s(dk1[k], w2, acc2[1]);
                acc2[2] = fma2s(dk2[k], w2, acc2[2]);
                acc2[3] = fma2s(dk3[k], w2, acc2[3]);
            }
        }
        int dA = lane, dB = lane + 64;
        float scA = bn2_g[dA] * rsqrtf(bn2_v[dA] + 1e-5f);
        float shA = scA * (conv_b[dA] - bn2_m[dA]) + bn2_b[dA];
        float scB = bn2_g[dB] * rsqrtf(bn2_v[dB] + 1e-5f);
        float shB = scB * (conv_b[dB] - bn2_m[dB]) + bn2_b[dB];
        float4 rA, rB;
        rA.x = fmaxf(scA * acc2[0].x + shA, 0.f);
        rA.y = fmaxf(scA * acc2[1].x + shA, 0.f);
        rA.z = fmaxf(scA * acc2[2].x + shA, 0.f);
        rA.w = fmaxf(scA * acc2[3].x + shA, 0.f);
        rB.x = fmaxf(scB * acc2[0].y + shB, 0.f);
        rB.y = fmaxf(scB * acc2[1].y + shB, 0.f);
        rB.z = fmaxf(scB * acc2[2].y + shB, 0.f);
        rB.w = fmaxf(scB * acc2[3].y + shB, 0.f);
        size_t oA = (((size_t)(n * 128 + dA)) * 64 + h) * 64 + w0;
        size_t oB = (((size_t)(n * 128 + dB)) * 64 + h) * 64 + w0;
        *reinterpret_cast<float4*>(out + oA) = rA;
        *reinterpret_cast<float4*>(out + oB) = rB;
    }
}

extern "C" void kernel_launch(void* const* d_in, const int* in_sizes, int n_in,
                              void* d_out, int out_size, void* d_ws, size_t ws_size,
                              hipStream_t stream) {
    const float* x      = (const float*)d_in[0];
    const float* refl   = (const float*)d_in[1];
    const float* gw1    = (const float*)d_in[2];
    const float* gb1    = (const float*)d_in[3];
    const float* gw2    = (const float*)d_in[4];
    const float* gb2    = (const float*)d_in[5];
    const float* tap_w  = (const float*)d_in[6];
    const float* tap_b  = (const float*)d_in[7];
    const float* dw_w   = (const float*)d_in[8];
    const float* dw_b   = (const float*)d_in[9];
    const float* ln_g   = (const float*)d_in[10];
    const float* ln_b   = (const float*)d_in[11];
    const float* inp_w  = (const float*)d_in[12];
    const float* inp_b  = (const float*)d_in[13];
    const float* off_w  = (const float*)d_in[14];
    const float* off_b  = (const float*)d_in[15];
    const float* mask_w = (const float*)d_in[16];
    const float* mask_b = (const float*)d_in[17];
    const float* outp_w = (const float*)d_in[18];
    const float* outp_b = (const float*)d_in[19];
    const float* conv_w = (const float*)d_in[20];
    const float* conv_b = (const float*)d_in[21];
    const float* bn1_g  = (const float*)d_in[22];
    const float* bn1_b  = (const float*)d_in[23];
    const float* bn1_m  = (const float*)d_in[24];
    const float* bn1_v  = (const float*)d_in[25];
    const float* bn2_g  = (const float*)d_in[26];
    const float* bn2_b  = (const float*)d_in[27];
    const float* bn2_m  = (const float*)d_in[28];
    const float* bn2_v  = (const float*)d_in[29];

    // ws (floats): pooled 512 | xs 2,097,152 | xpad2 4,460,544 (paired) ≈ 26.2 MiB
    float* ws     = (float*)d_ws;
    float* pooled = ws;                    // 512
    float* xs     = ws + 512;              // 2,097,152  (NHWC)
    float* xpad2  = xs + 2097152;          // 8*66*66*128 (x-paired NHWC)

    k_pool<<<512, 256, 0, stream>>>(x, pooled);
    k_xsproj<<<512, 256, 0, stream>>>(x, refl, tap_w, tap_b, pooled,
                                      gw1, gb1, gw2, gb2,
                                      inp_w, inp_b, xs, xpad2);
    k_dwsamp<<<4096, 128, 0, stream>>>(xs, xpad2, dw_w, dw_b, ln_g, ln_b,
                                       off_w, off_b, mask_w, mask_b,
                                       outp_w, outp_b, bn1_g, bn1_b, bn1_m, bn1_v,
                                       conv_w, conv_b, bn2_g, bn2_b, bn2_m, bn2_v,
                                       (float*)d_out);
}